// Round 4
// baseline (269.558 us; speedup 1.0000x reference)
//
#include <hip/hip_runtime.h>

typedef __bf16 bf16_t;
typedef __bf16 bf16x8 __attribute__((ext_vector_type(8)));
typedef float f32x4 __attribute__((ext_vector_type(4)));

#define B_ 2
#define H_ 16
#define D_ 64
#define E_ 1024
#define QL 1024
#define KL 2048
#define SCALE_ 0.125f
#define NEG_BIG -1e30f

// ---------------- async global->LDS (CK-style addrspace casts) ----------------
__device__ __forceinline__ void gload_lds16(const void* g, void* lds) {
  auto* gp = reinterpret_cast<const __attribute__((address_space(1))) uint32_t*>(
      reinterpret_cast<uintptr_t>(g));
  auto* lp = reinterpret_cast<__attribute__((address_space(3))) uint32_t*>(
      reinterpret_cast<uintptr_t>(lds));
  __builtin_amdgcn_global_load_lds(gp, lp, 16, 0, 0);
}

// ---------------- fp32 -> bf16 cast (8 elems/thread, exact grid) ----------------
__global__ __launch_bounds__(256) void cast_bf16_k(const float* __restrict__ in,
                                                   bf16_t* __restrict__ out) {
  size_t i = (size_t)blockIdx.x * 256 + threadIdx.x;
  float4 a = ((const float4*)in)[2 * i];
  float4 b = ((const float4*)in)[2 * i + 1];
  bf16x8 o;
  o[0] = (bf16_t)a.x; o[1] = (bf16_t)a.y; o[2] = (bf16_t)a.z; o[3] = (bf16_t)a.w;
  o[4] = (bf16_t)b.x; o[5] = (bf16_t)b.y; o[6] = (bf16_t)b.z; o[7] = (bf16_t)b.w;
  ((bf16x8*)out)[i] = o;
}

// ---------------- mask -> additive bias, dtype auto-detect ----------------
// bool/uint8: bytes at i%4!=0 are random nonzero. int32(0/1): only byte0 of each
// word nonzero. float32(0/1): only bytes 2,3 nonzero, byte0 always zero.
__global__ void prep_mask(const unsigned char* __restrict__ mraw, float* __restrict__ bias) {
  __shared__ int flagMis, flagB0;
  int t = threadIdx.x;
  if (t == 0) { flagMis = 0; flagB0 = 0; }
  __syncthreads();
  int a = 0, c = 0;
  for (int i = t; i < B_ * KL; i += 256) {
    if (i & 3) a |= mraw[i]; else c |= mraw[i];
  }
  if (a) atomicOr(&flagMis, 1);
  if (c) atomicOr(&flagB0, 1);
  __syncthreads();
  int mode = (flagMis == 0) ? 0 : (flagB0 ? 1 : 2);  // 0:int32 1:byte 2:float32
  for (int i = t; i < B_ * KL; i += 256) {
    int mv;
    if (mode == 0)      mv = ((const int*)mraw)[i];
    else if (mode == 1) mv = mraw[i];
    else                mv = (((const float*)mraw)[i] != 0.0f);
    bias[i] = mv ? NEG_BIG : 0.0f;
  }
}

// ---------------- GEMM C[M,N] = A[M,K] * W[N,K]^T + bias ----------------
// 128x128 tile, BK=64, 4 waves (64x64/wave, 4x4 16x16 frags), double-buffered
// LDS via global_load_lds w=16, XOR-swizzled (pre-swizzled global source).
// MODE 0: bf16 head-scatter store [B,H,L,D]; MODE 1: fp32 row-major store.
template <int MODE>
__global__ __launch_bounds__(256, 2)
void gemm_nt(const bf16_t* __restrict__ A, const bf16_t* __restrict__ W,
             const float* __restrict__ bias, void* __restrict__ Cout,
             int M, int N, int K, int Lshift) {
  __shared__ alignas(16) bf16_t As[2][128 * 64];
  __shared__ alignas(16) bf16_t Bs[2][128 * 64];
  const int tid = threadIdx.x;
  const int lane = tid & 63;
  const int w = tid >> 6;
  const int l15 = lane & 15, l4 = lane >> 4;
  const int wr = w >> 1, wc = w & 1;
  const int row0 = blockIdx.x * 128, col0 = blockIdx.y * 128;

  f32x4 acc[4][4] = {};

  auto stage = [&](int buf, int kt) {
    const int k0 = kt * 64;
#pragma unroll
    for (int i = 0; i < 4; ++i) {
      int idx = (w * 4 + i) * 64 + lane;
      int r = idx >> 3, c = idx & 7;
      int cs = ((c ^ (r & 7)) * 8);
      gload_lds16(A + (size_t)(row0 + r) * K + k0 + cs, &As[buf][(w * 4 + i) * 512]);
      gload_lds16(W + (size_t)(col0 + r) * K + k0 + cs, &Bs[buf][(w * 4 + i) * 512]);
    }
  };

  auto compute = [&](int buf) {
#pragma unroll
    for (int t = 0; t < 2; ++t) {
      bf16x8 af[4], bfv[4];
#pragma unroll
      for (int i = 0; i < 4; ++i) {
        int r = wr * 64 + i * 16 + l15;
        af[i] = *(const bf16x8*)&As[buf][r * 64 + (((t * 4 + l4) ^ (r & 7)) * 8)];
      }
#pragma unroll
      for (int j = 0; j < 4; ++j) {
        int r = wc * 64 + j * 16 + l15;
        bfv[j] = *(const bf16x8*)&Bs[buf][r * 64 + (((t * 4 + l4) ^ (r & 7)) * 8)];
      }
#pragma unroll
      for (int i = 0; i < 4; ++i)
#pragma unroll
        for (int j = 0; j < 4; ++j)
          acc[i][j] = __builtin_amdgcn_mfma_f32_16x16x32_bf16(af[i], bfv[j], acc[i][j], 0, 0, 0);
    }
  };

  stage(0, 0);
  const int nk = K >> 6;
  for (int kt = 0; kt < nk; ++kt) {
    __syncthreads();
    if (kt + 1 < nk) stage((kt + 1) & 1, kt + 1);
    compute(kt & 1);
  }

#pragma unroll
  for (int i = 0; i < 4; ++i) {
    int mbase = row0 + wr * 64 + i * 16 + l4 * 4;
#pragma unroll
    for (int j = 0; j < 4; ++j) {
      int n = col0 + wc * 64 + j * 16 + l15;
      float bv = bias[n];
#pragma unroll
      for (int r = 0; r < 4; ++r) {
        float v = acc[i][j][r] + bv;
        int m = mbase + r;
        if (MODE == 0) {
          int bi = m >> Lshift;
          int ml = m & ((1 << Lshift) - 1);
          size_t dst = ((((size_t)bi * H_ + (n >> 6)) << Lshift) + ml) * D_ + (n & 63);
          ((bf16_t*)Cout)[dst] = (bf16_t)v;
        } else {
          ((float*)Cout)[(size_t)m * N + n] = v;
        }
      }
    }
  }
}

// ---------------- fused flash attention ----------------
// grid (Q/64, H, B), 256 thr. Wave w owns 16 q-rows. KBLK=64.
// K in LDS (DMA, XOR-swz src); V transposed+swizzled at stage; P transposed
// through per-wave swizzled LDS. Online softmax with finite -1e30 mask bias.
__global__ __launch_bounds__(256, 2)
void attn_fused(const bf16_t* __restrict__ qh, const bf16_t* __restrict__ kh,
                const bf16_t* __restrict__ vh, const float* __restrict__ mbias,
                bf16_t* __restrict__ outx) {
  __shared__ alignas(16) bf16_t Ksm[64 * 64];
  __shared__ alignas(16) bf16_t Vt[64 * 64];
  __shared__ alignas(16) bf16_t Ps[4][16 * 64];

  const int qt = blockIdx.x, h = blockIdx.y, b = blockIdx.z;
  const int tid = threadIdx.x, lane = tid & 63, w = tid >> 6;
  const int l15 = lane & 15, l4 = lane >> 4;

  const size_t bh = (size_t)b * H_ + h;
  const bf16_t* qbase = qh + (bh * QL + qt * 64 + w * 16) * D_;
  bf16x8 qf[2];
#pragma unroll
  for (int t = 0; t < 2; ++t)
    qf[t] = *(const bf16x8*)(qbase + l15 * D_ + t * 32 + l4 * 8);

  float m_run[4], l_run[4];
  f32x4 o_acc[4] = {};
#pragma unroll
  for (int r = 0; r < 4; ++r) { m_run[r] = NEG_BIG; l_run[r] = 0.f; }

  const bf16_t* kbase = kh + bh * KL * D_;
  const bf16_t* vbase = vh + bh * KL * D_;
  const float* mrow = mbias + (size_t)b * KL;
  const int vk = tid >> 2, vc = tid & 3;

  for (int kt = 0; kt < KL / 64; ++kt) {
    // K tile: DMA with pre-swizzled source
#pragma unroll
    for (int i = 0; i < 2; ++i) {
      int idx = (w * 2 + i) * 64 + lane;
      int r = idx >> 3, c = idx & 7;
      gload_lds16(kbase + (size_t)(kt * 64 + r) * D_ + ((c ^ (r & 7)) * 8),
                  &Ksm[(w * 2 + i) * 512]);
    }
    // V tile transposed: Vt[d][k], swizzled chunk = (k>>3)^(d&7)
#pragma unroll
    for (int half = 0; half < 2; ++half) {
      int cc = vc + half * 4;
      bf16x8 vv = *(const bf16x8*)(vbase + (size_t)(kt * 64 + vk) * D_ + cc * 8);
#pragma unroll
      for (int e = 0; e < 8; ++e) {
        int d = cc * 8 + e;
        Vt[d * 64 + (((vk >> 3) ^ (d & 7)) * 8) + (vk & 7)] = vv[e];
      }
    }
    __syncthreads();

    // S = q K^T  (16 q-rows x 64 k-cols per wave)
    f32x4 s[4] = {};
#pragma unroll
    for (int ct = 0; ct < 4; ++ct) {
      int kcol = ct * 16 + l15;
#pragma unroll
      for (int t = 0; t < 2; ++t) {
        bf16x8 kf = *(const bf16x8*)&Ksm[kcol * 64 + (((t * 4 + l4) ^ (kcol & 7)) * 8)];
        s[ct] = __builtin_amdgcn_mfma_f32_16x16x32_bf16(qf[t], kf, s[ct], 0, 0, 0);
      }
    }

    float sv[4][4];
#pragma unroll
    for (int ct = 0; ct < 4; ++ct) {
      float mv = mrow[kt * 64 + ct * 16 + l15];
#pragma unroll
      for (int r = 0; r < 4; ++r) sv[ct][r] = s[ct][r] * SCALE_ + mv;
    }

    float mt[4];
#pragma unroll
    for (int r = 0; r < 4; ++r)
      mt[r] = fmaxf(fmaxf(sv[0][r], sv[1][r]), fmaxf(sv[2][r], sv[3][r]));
#pragma unroll
    for (int off = 1; off < 16; off <<= 1) {
#pragma unroll
      for (int r = 0; r < 4; ++r) mt[r] = fmaxf(mt[r], __shfl_xor(mt[r], off, 64));
    }

    float alpha[4];
#pragma unroll
    for (int r = 0; r < 4; ++r) {
      float mnew = fmaxf(m_run[r], mt[r]);
      alpha[r] = __expf(m_run[r] - mnew);
      m_run[r] = mnew;
    }

    float rsum[4] = {0.f, 0.f, 0.f, 0.f};
#pragma unroll
    for (int ct = 0; ct < 4; ++ct) {
      int k = ct * 16 + l15;
#pragma unroll
      for (int r = 0; r < 4; ++r) {
        float p = __expf(sv[ct][r] - m_run[r]);
        rsum[r] += p;
        int q = l4 * 4 + r;
        Ps[w][q * 64 + (((k >> 3) ^ (q & 7)) * 8) + (k & 7)] = (bf16_t)p;
      }
    }
#pragma unroll
    for (int off = 1; off < 16; off <<= 1) {
#pragma unroll
      for (int r = 0; r < 4; ++r) rsum[r] += __shfl_xor(rsum[r], off, 64);
    }
#pragma unroll
    for (int r = 0; r < 4; ++r) l_run[r] = l_run[r] * alpha[r] + rsum[r];

#pragma unroll
    for (int dt = 0; dt < 4; ++dt)
#pragma unroll
      for (int r = 0; r < 4; ++r) o_acc[dt][r] *= alpha[r];

    // O += P V
#pragma unroll
    for (int kkh = 0; kkh < 2; ++kkh) {
      bf16x8 pa = *(const bf16x8*)&Ps[w][l15 * 64 + (((kkh * 4 + l4) ^ (l15 & 7)) * 8)];
#pragma unroll
      for (int dt = 0; dt < 4; ++dt) {
        int d = dt * 16 + l15;
        bf16x8 vf = *(const bf16x8*)&Vt[d * 64 + (((kkh * 4 + l4) ^ (d & 7)) * 8)];
        o_acc[dt] = __builtin_amdgcn_mfma_f32_16x16x32_bf16(pa, vf, o_acc[dt], 0, 0, 0);
      }
    }
    __syncthreads();
  }

#pragma unroll
  for (int r = 0; r < 4; ++r) {
    float inv = 1.0f / l_run[r];
    int qrow = qt * 64 + w * 16 + l4 * 4 + r;
#pragma unroll
    for (int dt = 0; dt < 4; ++dt) {
      int d = dt * 16 + l15;
      outx[((size_t)b * QL + qrow) * E_ + h * D_ + d] = (bf16_t)(o_acc[dt][r] * inv);
    }
  }
}

// ---------------- host ----------------
extern "C" void kernel_launch(void* const* d_in, const int* in_sizes, int n_in,
                              void* d_out, int out_size, void* d_ws, size_t ws_size,
                              hipStream_t stream) {
  const float* query = (const float*)d_in[0];
  const float* key   = (const float*)d_in[1];
  const float* value = (const float*)d_in[2];
  const void*  mask  = d_in[3];
  const float* Wq = (const float*)d_in[4];
  const float* bq = (const float*)d_in[5];
  const float* Wk = (const float*)d_in[6];
  const float* bk = (const float*)d_in[7];
  const float* Wv = (const float*)d_in[8];
  const float* bv = (const float*)d_in[9];
  const float* Wo = (const float*)d_in[10];
  const float* bo = (const float*)d_in[11];

  char* ws = (char*)d_ws;
  bf16_t* Xq  = (bf16_t*)(ws + (0ull  << 20));  // 4 MB  [2048][1024]
  bf16_t* Xk  = (bf16_t*)(ws + (4ull  << 20));  // 8 MB  [4096][1024]
  bf16_t* Xv  = (bf16_t*)(ws + (12ull << 20));  // 8 MB
  bf16_t* Wqb = (bf16_t*)(ws + (20ull << 20));  // 2 MB
  bf16_t* Wkb = (bf16_t*)(ws + (22ull << 20));
  bf16_t* Wvb = (bf16_t*)(ws + (24ull << 20));
  bf16_t* Wob = (bf16_t*)(ws + (26ull << 20));
  bf16_t* qhd = (bf16_t*)(ws + (28ull << 20));  // 4 MB  [B,H,QL,D]
  bf16_t* khd = (bf16_t*)(ws + (32ull << 20));  // 8 MB  [B,H,KL,D]
  bf16_t* vhd = (bf16_t*)(ws + (40ull << 20));  // 8 MB
  bf16_t* axo = (bf16_t*)(ws + (48ull << 20));  // 4 MB  [2048][1024]
  float*  mbias = (float*)(ws + (52ull << 20)); // 16 KB

  dim3 blk(256);
  prep_mask<<<1, blk, 0, stream>>>((const unsigned char*)mask, mbias);
  cast_bf16_k<<<(2 * QL * E_) / 2048, blk, 0, stream>>>(query, Xq);
  cast_bf16_k<<<(2 * KL * E_) / 2048, blk, 0, stream>>>(key, Xk);
  cast_bf16_k<<<(2 * KL * E_) / 2048, blk, 0, stream>>>(value, Xv);
  cast_bf16_k<<<(E_ * E_) / 2048, blk, 0, stream>>>(Wq, Wqb);
  cast_bf16_k<<<(E_ * E_) / 2048, blk, 0, stream>>>(Wk, Wkb);
  cast_bf16_k<<<(E_ * E_) / 2048, blk, 0, stream>>>(Wv, Wvb);
  cast_bf16_k<<<(E_ * E_) / 2048, blk, 0, stream>>>(Wo, Wob);

  gemm_nt<0><<<dim3(16, 8), blk, 0, stream>>>(Xq, Wqb, bq, qhd, 2048, 1024, 1024, 10);
  gemm_nt<0><<<dim3(32, 8), blk, 0, stream>>>(Xk, Wkb, bk, khd, 4096, 1024, 1024, 11);
  gemm_nt<0><<<dim3(32, 8), blk, 0, stream>>>(Xv, Wvb, bv, vhd, 4096, 1024, 1024, 11);

  attn_fused<<<dim3(QL / 64, H_, B_), blk, 0, stream>>>(qhd, khd, vhd, mbias, axo);

  gemm_nt<1><<<dim3(16, 8), blk, 0, stream>>>(axo, Wob, bo, (float*)d_out, 2048, 1024, 1024, 0);
}

// Round 5
// 232.605 us; speedup vs baseline: 1.1589x; 1.1589x over previous
//
#include <hip/hip_runtime.h>

typedef __bf16 bf16_t;
typedef __bf16 bf16x4 __attribute__((ext_vector_type(4)));
typedef __bf16 bf16x8 __attribute__((ext_vector_type(8)));
typedef float f32x4 __attribute__((ext_vector_type(4)));

#define B_ 2
#define H_ 16
#define D_ 64
#define E_ 1024
#define QL 1024
#define KL 2048
#define SCALE_L2E 0.1803368801111204f  /* 0.125 * log2(e) — softmax in exp2 domain */
#define NEG_BIG -1e30f

// ---------------- async global->LDS ----------------
__device__ __forceinline__ void gload_lds16(const void* g, void* lds) {
  auto* gp = reinterpret_cast<const __attribute__((address_space(1))) uint32_t*>(
      reinterpret_cast<uintptr_t>(g));
  auto* lp = reinterpret_cast<__attribute__((address_space(3))) uint32_t*>(
      reinterpret_cast<uintptr_t>(lds));
  __builtin_amdgcn_global_load_lds(gp, lp, 16, 0, 0);
}

// ---------------- fp32 -> bf16 casts ----------------
__global__ __launch_bounds__(256) void cast_bf16_k(const float* __restrict__ in,
                                                   bf16_t* __restrict__ out) {
  size_t i = (size_t)blockIdx.x * 256 + threadIdx.x;
  float4 a = ((const float4*)in)[2 * i];
  float4 b = ((const float4*)in)[2 * i + 1];
  bf16x8 o;
  o[0] = (bf16_t)a.x; o[1] = (bf16_t)a.y; o[2] = (bf16_t)a.z; o[3] = (bf16_t)a.w;
  o[4] = (bf16_t)b.x; o[5] = (bf16_t)b.y; o[6] = (bf16_t)b.z; o[7] = (bf16_t)b.w;
  ((bf16x8*)out)[i] = o;
}

// 4 weight matrices in one launch: grid (512, 4)
__global__ __launch_bounds__(256) void cast4_k(const float* __restrict__ w0, const float* __restrict__ w1,
                                               const float* __restrict__ w2, const float* __restrict__ w3,
                                               bf16_t* __restrict__ o0, bf16_t* __restrict__ o1,
                                               bf16_t* __restrict__ o2, bf16_t* __restrict__ o3) {
  int seg = blockIdx.y;
  const float* in = (seg == 0) ? w0 : (seg == 1) ? w1 : (seg == 2) ? w2 : w3;
  bf16_t* out = (seg == 0) ? o0 : (seg == 1) ? o1 : (seg == 2) ? o2 : o3;
  size_t i = (size_t)blockIdx.x * 256 + threadIdx.x;
  float4 a = ((const float4*)in)[2 * i];
  float4 b = ((const float4*)in)[2 * i + 1];
  bf16x8 o;
  o[0] = (bf16_t)a.x; o[1] = (bf16_t)a.y; o[2] = (bf16_t)a.z; o[3] = (bf16_t)a.w;
  o[4] = (bf16_t)b.x; o[5] = (bf16_t)b.y; o[6] = (bf16_t)b.z; o[7] = (bf16_t)b.w;
  ((bf16x8*)out)[i] = o;
}

// ---------------- mask -> additive bias, dtype auto-detect ----------------
__global__ void prep_mask(const unsigned char* __restrict__ mraw, float* __restrict__ bias) {
  __shared__ int flagMis, flagB0;
  int t = threadIdx.x;
  if (t == 0) { flagMis = 0; flagB0 = 0; }
  __syncthreads();
  int a = 0, c = 0;
  for (int i = t; i < B_ * KL; i += 256) {
    if (i & 3) a |= mraw[i]; else c |= mraw[i];
  }
  if (a) atomicOr(&flagMis, 1);
  if (c) atomicOr(&flagB0, 1);
  __syncthreads();
  int mode = (flagMis == 0) ? 0 : (flagB0 ? 1 : 2);  // 0:int32 1:byte 2:float32
  for (int i = t; i < B_ * KL; i += 256) {
    int mv;
    if (mode == 0)      mv = ((const int*)mraw)[i];
    else if (mode == 1) mv = mraw[i];
    else                mv = (((const float*)mraw)[i] != 0.0f);
    bias[i] = mv ? NEG_BIG : 0.0f;
  }
}

// ---------------- GEMM C = A[M,K] * W[N,K]^T + bias ----------------
// MODE 0: bf16 head-scatter store [B,H,L,D] (bias per n)
// MODE 1: fp32 row-major store [M,N]        (bias per n)
// MODE 2: bf16 transposed head store: m=feature(h*64+d), n=seq(b*KL+k),
//         dst [B,H,D,KL]                    (bias per m)
template <int MODE>
__global__ __launch_bounds__(256, 2)
void gemm_nt(const bf16_t* __restrict__ A, const bf16_t* __restrict__ W,
             const float* __restrict__ bias, void* __restrict__ Cout,
             int M, int N, int K, int Lshift) {
  __shared__ alignas(16) bf16_t As[2][128 * 64];
  __shared__ alignas(16) bf16_t Bs[2][128 * 64];
  const int tid = threadIdx.x;
  const int lane = tid & 63;
  const int w = tid >> 6;
  const int l15 = lane & 15, l4 = lane >> 4;
  const int wr = w >> 1, wc = w & 1;
  const int row0 = blockIdx.x * 128, col0 = blockIdx.y * 128;

  f32x4 acc[4][4] = {};

  auto stage = [&](int buf, int kt) {
    const int k0 = kt * 64;
#pragma unroll
    for (int i = 0; i < 4; ++i) {
      int idx = (w * 4 + i) * 64 + lane;
      int r = idx >> 3, c = idx & 7;
      int cs = ((c ^ (r & 7)) * 8);
      gload_lds16(A + (size_t)(row0 + r) * K + k0 + cs, &As[buf][(w * 4 + i) * 512]);
      gload_lds16(W + (size_t)(col0 + r) * K + k0 + cs, &Bs[buf][(w * 4 + i) * 512]);
    }
  };

  auto compute = [&](int buf) {
#pragma unroll
    for (int t = 0; t < 2; ++t) {
      bf16x8 af[4], bfv[4];
#pragma unroll
      for (int i = 0; i < 4; ++i) {
        int r = wr * 64 + i * 16 + l15;
        af[i] = *(const bf16x8*)&As[buf][r * 64 + (((t * 4 + l4) ^ (r & 7)) * 8)];
      }
#pragma unroll
      for (int j = 0; j < 4; ++j) {
        int r = wc * 64 + j * 16 + l15;
        bfv[j] = *(const bf16x8*)&Bs[buf][r * 64 + (((t * 4 + l4) ^ (r & 7)) * 8)];
      }
#pragma unroll
      for (int i = 0; i < 4; ++i)
#pragma unroll
        for (int j = 0; j < 4; ++j)
          acc[i][j] = __builtin_amdgcn_mfma_f32_16x16x32_bf16(af[i], bfv[j], acc[i][j], 0, 0, 0);
    }
  };

  stage(0, 0);
  const int nk = K >> 6;
  for (int kt = 0; kt < nk; ++kt) {
    __syncthreads();
    if (kt + 1 < nk) stage((kt + 1) & 1, kt + 1);
    compute(kt & 1);
  }

#pragma unroll
  for (int i = 0; i < 4; ++i) {
    int mbase = row0 + wr * 64 + i * 16 + l4 * 4;
    f32x4 bvm = {};
    if (MODE == 2) bvm = *(const f32x4*)&bias[mbase];
#pragma unroll
    for (int j = 0; j < 4; ++j) {
      int n = col0 + wc * 64 + j * 16 + l15;
      float bv = (MODE == 2) ? 0.f : bias[n];
#pragma unroll
      for (int r = 0; r < 4; ++r) {
        float v = acc[i][j][r] + ((MODE == 2) ? bvm[r] : bv);
        int m = mbase + r;
        if (MODE == 0) {
          int bi = m >> Lshift;
          int ml = m & ((1 << Lshift) - 1);
          size_t dst = ((((size_t)bi * H_ + (n >> 6)) << Lshift) + ml) * D_ + (n & 63);
          ((bf16_t*)Cout)[dst] = (bf16_t)v;
        } else if (MODE == 1) {
          ((float*)Cout)[(size_t)m * N + n] = v;
        } else {
          int hh = m >> 6, d = m & 63;
          int bi = n >> 11, k = n & (KL - 1);
          ((bf16_t*)Cout)[((((size_t)bi * H_ + hh) << 6) + d) * KL + k] = (bf16_t)v;
        }
      }
    }
  }
}

// ---------------- fused flash attention (swapped QK^T, V^T input) ----------------
// grid (QL/32, H, B), 128 thr (2 waves, 16 q-rows each). KVBLK=64, dbuf DMA.
// S^T = mfma(K,Q): thread holds P[k=ct*16+l4*4+r][q=l15] -> per-lane scalar
// softmax state, 2-shuffle reduce, b64 P-store with XOR swizzle, 1 barrier/tile.
__global__ __launch_bounds__(128, 2)
void attn_fused(const bf16_t* __restrict__ qh, const bf16_t* __restrict__ kh,
                const bf16_t* __restrict__ vhT, const float* __restrict__ mbias,
                bf16_t* __restrict__ outx) {
  __shared__ alignas(16) bf16_t Ksm[2][64 * 64];
  __shared__ alignas(16) bf16_t Vt[2][64 * 64];
  __shared__ alignas(16) bf16_t Ps[2][16 * 64];

  const int qt = blockIdx.x, h = blockIdx.y, b = blockIdx.z;
  const int tid = threadIdx.x, lane = tid & 63, w = tid >> 6;
  const int l15 = lane & 15, l4 = lane >> 4;
  const size_t bh = (size_t)b * H_ + h;

  const bf16_t* qbase = qh + (bh * QL + qt * 32 + w * 16) * D_;
  bf16x8 qf[2];
#pragma unroll
  for (int t = 0; t < 2; ++t)
    qf[t] = *(const bf16x8*)(qbase + l15 * D_ + t * 32 + l4 * 8);

  float m_run = NEG_BIG, l_run = 0.f;
  f32x4 o_acc[4] = {};

  const bf16_t* kbase = kh + bh * KL * D_;
  const bf16_t* vtb = vhT + bh * (size_t)D_ * KL;
  const float* mrow = mbias + (size_t)b * KL;

  auto stage = [&](int bufsel, int kt) {
#pragma unroll
    for (int i = 0; i < 4; ++i) {
      int idx = (w * 4 + i) * 64 + lane;  // 0..511 chunk id
      int r = idx >> 3, c = idx & 7;
      int cs = (c ^ (r & 7)) * 8;
      gload_lds16(kbase + (size_t)(kt * 64 + r) * D_ + cs, &Ksm[bufsel][idx * 8]);
      gload_lds16(vtb + (size_t)r * KL + kt * 64 + cs, &Vt[bufsel][idx * 8]);
    }
  };

  stage(0, 0);
  __syncthreads();

  for (int kt = 0; kt < KL / 64; ++kt) {
    const int buf = kt & 1;
    if (kt + 1 < KL / 64) stage(buf ^ 1, kt + 1);

    f32x4 mv[4];
#pragma unroll
    for (int ct = 0; ct < 4; ++ct)
      mv[ct] = *(const f32x4*)&mrow[kt * 64 + ct * 16 + l4 * 4];

    // S^T tile: rows k, cols q
    f32x4 s[4] = {};
#pragma unroll
    for (int ct = 0; ct < 4; ++ct) {
      int krow = ct * 16 + l15;
#pragma unroll
      for (int t = 0; t < 2; ++t) {
        bf16x8 kf = *(const bf16x8*)&Ksm[buf][krow * 64 + (((t * 4 + l4) ^ (krow & 7)) * 8)];
        s[ct] = __builtin_amdgcn_mfma_f32_16x16x32_bf16(kf, qf[t], s[ct], 0, 0, 0);
      }
    }

    // per-lane online softmax for q = l15 (exp2 domain)
    float sv[4][4];
    float mt = NEG_BIG;
#pragma unroll
    for (int ct = 0; ct < 4; ++ct)
#pragma unroll
      for (int r = 0; r < 4; ++r) {
        float x = s[ct][r] * SCALE_L2E + mv[ct][r];
        sv[ct][r] = x;
        mt = fmaxf(mt, x);
      }
    mt = fmaxf(mt, __shfl_xor(mt, 16, 64));
    mt = fmaxf(mt, __shfl_xor(mt, 32, 64));
    float mnew = fmaxf(m_run, mt);
    float alpha = exp2f(m_run - mnew);
    m_run = mnew;
    float rsum = 0.f;
#pragma unroll
    for (int ct = 0; ct < 4; ++ct)
#pragma unroll
      for (int r = 0; r < 4; ++r) {
        float p = exp2f(sv[ct][r] - mnew);
        sv[ct][r] = p;
        rsum += p;
      }
    rsum += __shfl_xor(rsum, 16, 64);
    rsum += __shfl_xor(rsum, 32, 64);
    l_run = l_run * alpha + rsum;

    // P store: row q=l15, k-chunk (ct*4+l4) XOR-swizzled, b64 writes
    char* psrow = (char*)&Ps[w][0] + l15 * 128;
#pragma unroll
    for (int ct = 0; ct < 4; ++ct) {
      bf16x4 pk;
#pragma unroll
      for (int r = 0; r < 4; ++r) pk[r] = (bf16_t)sv[ct][r];
      *(bf16x4*)(psrow + (((ct * 4 + l4) ^ l15) * 8)) = pk;
    }

    // rescale O rows (alpha for q=l4*4+r lives in lane l4*4+r)
    float arow[4];
#pragma unroll
    for (int r = 0; r < 4; ++r) arow[r] = __shfl(alpha, l4 * 4 + r, 64);
#pragma unroll
    for (int dt = 0; dt < 4; ++dt)
#pragma unroll
      for (int r = 0; r < 4; ++r) o_acc[dt][r] *= arow[r];

    // O += P V
#pragma unroll
    for (int t = 0; t < 2; ++t) {
      int c0 = t * 8 + l4 * 2;
      bf16x4 plo = *(const bf16x4*)(psrow + ((c0 ^ l15) * 8));
      bf16x4 phi = *(const bf16x4*)(psrow + (((c0 + 1) ^ l15) * 8));
      bf16x8 pa;
#pragma unroll
      for (int j = 0; j < 4; ++j) { pa[j] = plo[j]; pa[j + 4] = phi[j]; }
#pragma unroll
      for (int dt = 0; dt < 4; ++dt) {
        int d = dt * 16 + l15;
        bf16x8 vf = *(const bf16x8*)&Vt[buf][d * 64 + (((t * 4 + l4) ^ (d & 7)) * 8)];
        o_acc[dt] = __builtin_amdgcn_mfma_f32_16x16x32_bf16(pa, vf, o_acc[dt], 0, 0, 0);
      }
    }
    __syncthreads();
  }

  float inv = 1.0f / l_run;
  float irow[4];
#pragma unroll
  for (int r = 0; r < 4; ++r) irow[r] = __shfl(inv, l4 * 4 + r, 64);
#pragma unroll
  for (int r = 0; r < 4; ++r) {
    int qrow = qt * 32 + w * 16 + l4 * 4 + r;
#pragma unroll
    for (int dt = 0; dt < 4; ++dt) {
      int d = dt * 16 + l15;
      outx[((size_t)b * QL + qrow) * E_ + h * D_ + d] = (bf16_t)(o_acc[dt][r] * irow[r]);
    }
  }
}

// ---------------- host ----------------
extern "C" void kernel_launch(void* const* d_in, const int* in_sizes, int n_in,
                              void* d_out, int out_size, void* d_ws, size_t ws_size,
                              hipStream_t stream) {
  const float* query = (const float*)d_in[0];
  const float* key   = (const float*)d_in[1];
  const float* value = (const float*)d_in[2];
  const void*  mask  = d_in[3];
  const float* Wq = (const float*)d_in[4];
  const float* bq = (const float*)d_in[5];
  const float* Wk = (const float*)d_in[6];
  const float* bk = (const float*)d_in[7];
  const float* Wv = (const float*)d_in[8];
  const float* bv = (const float*)d_in[9];
  const float* Wo = (const float*)d_in[10];
  const float* bo = (const float*)d_in[11];

  char* ws = (char*)d_ws;
  bf16_t* Xq  = (bf16_t*)(ws + (0ull  << 20));  // 4 MB  [2048][1024]
  bf16_t* Xk  = (bf16_t*)(ws + (4ull  << 20));  // 8 MB  [4096][1024]
  bf16_t* Xv  = (bf16_t*)(ws + (12ull << 20));  // 8 MB
  bf16_t* Wqb = (bf16_t*)(ws + (20ull << 20));  // 2 MB
  bf16_t* Wkb = (bf16_t*)(ws + (22ull << 20));
  bf16_t* Wvb = (bf16_t*)(ws + (24ull << 20));
  bf16_t* Wob = (bf16_t*)(ws + (26ull << 20));
  bf16_t* qhd = (bf16_t*)(ws + (28ull << 20));  // 4 MB  [B,H,QL,D]
  bf16_t* khd = (bf16_t*)(ws + (32ull << 20));  // 8 MB  [B,H,KL,D]
  bf16_t* vht = (bf16_t*)(ws + (40ull << 20));  // 8 MB  [B,H,D,KL]  (V^T)
  bf16_t* axo = (bf16_t*)(ws + (48ull << 20));  // 4 MB  [2048][1024]
  float*  mbias = (float*)(ws + (52ull << 20)); // 16 KB

  dim3 blk(256);
  prep_mask<<<1, blk, 0, stream>>>((const unsigned char*)mask, mbias);
  cast_bf16_k<<<(2 * QL * E_) / 2048, blk, 0, stream>>>(query, Xq);
  cast_bf16_k<<<(2 * KL * E_) / 2048, blk, 0, stream>>>(key, Xk);
  cast_bf16_k<<<(2 * KL * E_) / 2048, blk, 0, stream>>>(value, Xv);
  cast4_k<<<dim3((E_ * E_) / 2048, 4), blk, 0, stream>>>(Wq, Wk, Wv, Wo, Wqb, Wkb, Wvb, Wob);

  gemm_nt<0><<<dim3(16, 8), blk, 0, stream>>>(Xq, Wqb, bq, qhd, 2048, 1024, 1024, 10);
  gemm_nt<0><<<dim3(32, 8), blk, 0, stream>>>(Xk, Wkb, bk, khd, 4096, 1024, 1024, 11);
  // V^T = Wv * Xv^T  (operand-swapped; MODE 2 stores [B,H,D,KL] with per-feature bias)
  gemm_nt<2><<<dim3(8, 32), blk, 0, stream>>>(Wvb, Xv, bv, vht, 1024, 4096, 1024, 0);

  attn_fused<<<dim3(QL / 32, H_, B_), dim3(128), 0, stream>>>(qhd, khd, vht, mbias, axo);

  gemm_nt<1><<<dim3(16, 8), blk, 0, stream>>>(axo, Wob, bo, (float*)d_out, 2048, 1024, 1024, 0);
}

// Round 7
// 211.278 us; speedup vs baseline: 1.2758x; 1.1009x over previous
//
#include <hip/hip_runtime.h>

typedef __bf16 bf16_t;
typedef __bf16 bf16x4 __attribute__((ext_vector_type(4)));
typedef __bf16 bf16x8 __attribute__((ext_vector_type(8)));
typedef float f32x4 __attribute__((ext_vector_type(4)));

#define B_ 2
#define H_ 16
#define D_ 64
#define E_ 1024
#define QL 1024
#define KL 2048
#define SCALE_L2E 0.1803368801111204f  /* 0.125 * log2(e) — softmax in exp2 domain */
#define NEG_BIG -1e30f
#define DEFER_THR 8.0f

// ---------------- async global->LDS ----------------
__device__ __forceinline__ void gload_lds16(const void* g, void* lds) {
  auto* gp = reinterpret_cast<const __attribute__((address_space(1))) uint32_t*>(
      reinterpret_cast<uintptr_t>(g));
  auto* lp = reinterpret_cast<__attribute__((address_space(3))) uint32_t*>(
      reinterpret_cast<uintptr_t>(lds));
  __builtin_amdgcn_global_load_lds(gp, lp, 16, 0, 0);
}

// ---------------- all fp32->bf16 casts in ONE kernel (grid 7168) ----------------
__global__ __launch_bounds__(256) void cast_all(
    const float* __restrict__ q, const float* __restrict__ k, const float* __restrict__ v,
    const float* __restrict__ wq, const float* __restrict__ wk,
    const float* __restrict__ wv, const float* __restrict__ wo,
    bf16_t* __restrict__ oq, bf16_t* __restrict__ ok, bf16_t* __restrict__ ov,
    bf16_t* __restrict__ owq, bf16_t* __restrict__ owk,
    bf16_t* __restrict__ owv, bf16_t* __restrict__ owo) {
  int blk = blockIdx.x;
  const float* in; bf16_t* out; int base;
  if (blk < 1024)      { in = q;  out = oq;  base = blk; }
  else if (blk < 3072) { in = k;  out = ok;  base = blk - 1024; }
  else if (blk < 5120) { in = v;  out = ov;  base = blk - 3072; }
  else if (blk < 5632) { in = wq; out = owq; base = blk - 5120; }
  else if (blk < 6144) { in = wk; out = owk; base = blk - 5632; }
  else if (blk < 6656) { in = wv; out = owv; base = blk - 6144; }
  else                 { in = wo; out = owo; base = blk - 6656; }
  size_t i = (size_t)base * 256 + threadIdx.x;
  float4 a = ((const float4*)in)[2 * i];
  float4 b = ((const float4*)in)[2 * i + 1];
  bf16x8 o;
  o[0] = (bf16_t)a.x; o[1] = (bf16_t)a.y; o[2] = (bf16_t)a.z; o[3] = (bf16_t)a.w;
  o[4] = (bf16_t)b.x; o[5] = (bf16_t)b.y; o[6] = (bf16_t)b.z; o[7] = (bf16_t)b.w;
  ((bf16x8*)out)[i] = o;
}

// ---------------- mask -> additive bias, dtype auto-detect ----------------
__global__ void prep_mask(const unsigned char* __restrict__ mraw, float* __restrict__ bias) {
  __shared__ int flagMis, flagB0;
  int t = threadIdx.x;
  if (t == 0) { flagMis = 0; flagB0 = 0; }
  __syncthreads();
  int a = 0, c = 0;
  for (int i = t; i < B_ * KL; i += 256) {
    if (i & 3) a |= mraw[i]; else c |= mraw[i];
  }
  if (a) atomicOr(&flagMis, 1);
  if (c) atomicOr(&flagB0, 1);
  __syncthreads();
  int mode = (flagMis == 0) ? 0 : (flagB0 ? 1 : 2);  // 0:int32 1:byte 2:float32
  for (int i = t; i < B_ * KL; i += 256) {
    int mv;
    if (mode == 0)      mv = ((const int*)mraw)[i];
    else if (mode == 1) mv = mraw[i];
    else                mv = (((const float*)mraw)[i] != 0.0f);
    bias[i] = mv ? NEG_BIG : 0.0f;
  }
}

// ---------------- fused Q/K/V projection GEMMs, one launch (grid 640) ----------------
// work<128: Q = Xq*Wq^T   -> bf16 [B,H,QL,D]   (mode 0, Lshift 10)
// work<384: K = Xk*Wk^T   -> bf16 [B,H,KL,D]   (mode 0, Lshift 11)
// else    : V^T = Wv*Xv^T -> bf16 [B,H,D,KL]   (mode 2, bias per-m)
__global__ __launch_bounds__(256, 2)
void qkv_gemm(const bf16_t* __restrict__ Xq, const bf16_t* __restrict__ Xk,
              const bf16_t* __restrict__ Xv, const bf16_t* __restrict__ Wqb,
              const bf16_t* __restrict__ Wkb, const bf16_t* __restrict__ Wvb,
              const float* __restrict__ bq, const float* __restrict__ bk,
              const float* __restrict__ bv,
              bf16_t* __restrict__ qhd, bf16_t* __restrict__ khd, bf16_t* __restrict__ vht) {
  __shared__ alignas(16) bf16_t As[2][128 * 64];
  __shared__ alignas(16) bf16_t Bs[2][128 * 64];
  const int wid = blockIdx.x;
  const int work = (wid & 7) * 80 + (wid >> 3);  // XCD-chunked (640 = 8*80)

  const bf16_t *A, *W;
  const float* bias;
  bf16_t* out;
  int mode, Lshift, row0, col0;
  if (work < 128) {
    A = Xq; W = Wqb; bias = bq; out = qhd; mode = 0; Lshift = 10;
    row0 = (work >> 3) * 128; col0 = (work & 7) * 128;
  } else if (work < 384) {
    int t = work - 128;
    A = Xk; W = Wkb; bias = bk; out = khd; mode = 0; Lshift = 11;
    row0 = (t >> 3) * 128; col0 = (t & 7) * 128;
  } else {
    int t = work - 384;
    A = Wvb; W = Xv; bias = bv; out = vht; mode = 2; Lshift = 0;
    row0 = (t & 7) * 128; col0 = (t >> 3) * 128;
  }

  const int K = 1024;
  const int tid = threadIdx.x;
  const int lane = tid & 63;
  const int w = tid >> 6;
  const int l15 = lane & 15, l4 = lane >> 4;
  const int wr = w >> 1, wc = w & 1;

  f32x4 acc[4][4] = {};

  auto stage = [&](int buf, int kt) {
    const int k0 = kt * 64;
#pragma unroll
    for (int i = 0; i < 4; ++i) {
      int idx = (w * 4 + i) * 64 + lane;
      int r = idx >> 3, c = idx & 7;
      int cs = ((c ^ (r & 7)) * 8);
      gload_lds16(A + (size_t)(row0 + r) * K + k0 + cs, &As[buf][(w * 4 + i) * 512]);
      gload_lds16(W + (size_t)(col0 + r) * K + k0 + cs, &Bs[buf][(w * 4 + i) * 512]);
    }
  };

  auto compute = [&](int buf) {
#pragma unroll
    for (int t = 0; t < 2; ++t) {
      bf16x8 af[4], bfv[4];
#pragma unroll
      for (int i = 0; i < 4; ++i) {
        int r = wr * 64 + i * 16 + l15;
        af[i] = *(const bf16x8*)&As[buf][r * 64 + (((t * 4 + l4) ^ (r & 7)) * 8)];
      }
#pragma unroll
      for (int j = 0; j < 4; ++j) {
        int r = wc * 64 + j * 16 + l15;
        bfv[j] = *(const bf16x8*)&Bs[buf][r * 64 + (((t * 4 + l4) ^ (r & 7)) * 8)];
      }
#pragma unroll
      for (int i = 0; i < 4; ++i)
#pragma unroll
        for (int j = 0; j < 4; ++j)
          acc[i][j] = __builtin_amdgcn_mfma_f32_16x16x32_bf16(af[i], bfv[j], acc[i][j], 0, 0, 0);
    }
  };

  stage(0, 0);
  const int nk = K >> 6;
  for (int kt = 0; kt < nk; ++kt) {
    __syncthreads();
    if (kt + 1 < nk) stage((kt + 1) & 1, kt + 1);
    compute(kt & 1);
  }

#pragma unroll
  for (int i = 0; i < 4; ++i) {
    int mbase = row0 + wr * 64 + i * 16 + l4 * 4;
    f32x4 bvm = {};
    if (mode == 2) bvm = *(const f32x4*)&bias[mbase];
#pragma unroll
    for (int j = 0; j < 4; ++j) {
      int n = col0 + wc * 64 + j * 16 + l15;
      float bv = (mode == 2) ? 0.f : bias[n];
#pragma unroll
      for (int r = 0; r < 4; ++r) {
        float v = acc[i][j][r] + ((mode == 2) ? bvm[r] : bv);
        int m = mbase + r;
        if (mode == 0) {
          int bi = m >> Lshift;
          int ml = m & ((1 << Lshift) - 1);
          size_t dst = ((((size_t)bi * H_ + (n >> 6)) << Lshift) + ml) * D_ + (n & 63);
          out[dst] = (bf16_t)v;
        } else {
          int hh = m >> 6, d = m & 63;
          int bi = n >> 11, kk = n & (KL - 1);
          out[((((size_t)bi * H_ + hh) << 6) + d) * KL + kk] = (bf16_t)v;
        }
      }
    }
  }
}

// ---------------- O projection GEMM (fp32 out) ----------------
template <int MODE>
__global__ __launch_bounds__(256, 2)
void gemm_nt(const bf16_t* __restrict__ A, const bf16_t* __restrict__ W,
             const float* __restrict__ bias, void* __restrict__ Cout,
             int M, int N, int K, int Lshift) {
  __shared__ alignas(16) bf16_t As[2][128 * 64];
  __shared__ alignas(16) bf16_t Bs[2][128 * 64];
  const int tid = threadIdx.x;
  const int lane = tid & 63;
  const int w = tid >> 6;
  const int l15 = lane & 15, l4 = lane >> 4;
  const int wr = w >> 1, wc = w & 1;
  const int row0 = blockIdx.x * 128, col0 = blockIdx.y * 128;

  f32x4 acc[4][4] = {};

  auto stage = [&](int buf, int kt) {
    const int k0 = kt * 64;
#pragma unroll
    for (int i = 0; i < 4; ++i) {
      int idx = (w * 4 + i) * 64 + lane;
      int r = idx >> 3, c = idx & 7;
      int cs = ((c ^ (r & 7)) * 8);
      gload_lds16(A + (size_t)(row0 + r) * K + k0 + cs, &As[buf][(w * 4 + i) * 512]);
      gload_lds16(W + (size_t)(col0 + r) * K + k0 + cs, &Bs[buf][(w * 4 + i) * 512]);
    }
  };

  auto compute = [&](int buf) {
#pragma unroll
    for (int t = 0; t < 2; ++t) {
      bf16x8 af[4], bfv[4];
#pragma unroll
      for (int i = 0; i < 4; ++i) {
        int r = wr * 64 + i * 16 + l15;
        af[i] = *(const bf16x8*)&As[buf][r * 64 + (((t * 4 + l4) ^ (r & 7)) * 8)];
      }
#pragma unroll
      for (int j = 0; j < 4; ++j) {
        int r = wc * 64 + j * 16 + l15;
        bfv[j] = *(const bf16x8*)&Bs[buf][r * 64 + (((t * 4 + l4) ^ (r & 7)) * 8)];
      }
#pragma unroll
      for (int i = 0; i < 4; ++i)
#pragma unroll
        for (int j = 0; j < 4; ++j)
          acc[i][j] = __builtin_amdgcn_mfma_f32_16x16x32_bf16(af[i], bfv[j], acc[i][j], 0, 0, 0);
    }
  };

  stage(0, 0);
  const int nk = K >> 6;
  for (int kt = 0; kt < nk; ++kt) {
    __syncthreads();
    if (kt + 1 < nk) stage((kt + 1) & 1, kt + 1);
    compute(kt & 1);
  }

#pragma unroll
  for (int i = 0; i < 4; ++i) {
    int mbase = row0 + wr * 64 + i * 16 + l4 * 4;
#pragma unroll
    for (int j = 0; j < 4; ++j) {
      int n = col0 + wc * 64 + j * 16 + l15;
      float bv = bias[n];
#pragma unroll
      for (int r = 0; r < 4; ++r) {
        float v = acc[i][j][r] + bv;
        int m = mbase + r;
        ((float*)Cout)[(size_t)m * N + n] = v;
      }
    }
  }
}

// ---------------- fused flash attention ----------------
// grid 1024 (flat, XCD-chunked so all 32 blocks of one (b,h) share an XCD L2).
// 128 thr (2 waves x 16 q-rows). Swapped QK^T (S^T), per-lane softmax state,
// defer-max (THR=8, exp2 domain) skips shuffles/alpha/rescale in steady state,
// deferred cross-lane l-reduction (alpha is q-uniform), setprio around MFMA.
__global__ __launch_bounds__(128, 2)
void attn_fused(const bf16_t* __restrict__ qh, const bf16_t* __restrict__ kh,
                const bf16_t* __restrict__ vhT, const float* __restrict__ mbias,
                bf16_t* __restrict__ outx) {
  __shared__ alignas(16) bf16_t Ksm[2][64 * 64];
  __shared__ alignas(16) bf16_t Vt[2][64 * 64];
  __shared__ alignas(16) bf16_t Ps[2][16 * 64];

  const int wid = blockIdx.x;
  const int work = (wid & 7) * 128 + (wid >> 3);  // 1024 = 8*128 bijective
  const int qt = work & 31;
  const int bh = work >> 5;          // blocks of one bh stay on one XCD
  const int h = bh & 15, b = bh >> 4;

  const int tid = threadIdx.x, lane = tid & 63, w = tid >> 6;
  const int l15 = lane & 15, l4 = lane >> 4;
  const size_t bhs = (size_t)b * H_ + h;

  const bf16_t* qbase = qh + (bhs * QL + qt * 32 + w * 16) * D_;
  bf16x8 qf[2];
#pragma unroll
  for (int t = 0; t < 2; ++t)
    qf[t] = *(const bf16x8*)(qbase + l15 * D_ + t * 32 + l4 * 8);

  float m_run = NEG_BIG, l_run = 0.f;
  f32x4 o_acc[4] = {};

  const bf16_t* kbase = kh + bhs * KL * D_;
  const bf16_t* vtb = vhT + bhs * (size_t)D_ * KL;
  const float* mrow = mbias + (size_t)b * KL;

  auto stage = [&](int bufsel, int kt) {
#pragma unroll
    for (int i = 0; i < 4; ++i) {
      int idx = (w * 4 + i) * 64 + lane;
      int r = idx >> 3, c = idx & 7;
      int cs = (c ^ (r & 7)) * 8;
      gload_lds16(kbase + (size_t)(kt * 64 + r) * D_ + cs, &Ksm[bufsel][idx * 8]);
      gload_lds16(vtb + (size_t)r * KL + kt * 64 + cs, &Vt[bufsel][idx * 8]);
    }
  };

  stage(0, 0);
  __syncthreads();

  for (int kt = 0; kt < KL / 64; ++kt) {
    const int buf = kt & 1;
    if (kt + 1 < KL / 64) stage(buf ^ 1, kt + 1);

    f32x4 mv[4];
#pragma unroll
    for (int ct = 0; ct < 4; ++ct)
      mv[ct] = *(const f32x4*)&mrow[kt * 64 + ct * 16 + l4 * 4];

    // S^T = K Q^T
    f32x4 s[4] = {};
    __builtin_amdgcn_s_setprio(1);
#pragma unroll
    for (int ct = 0; ct < 4; ++ct) {
      int krow = ct * 16 + l15;
#pragma unroll
      for (int t = 0; t < 2; ++t) {
        bf16x8 kf = *(const bf16x8*)&Ksm[buf][krow * 64 + (((t * 4 + l4) ^ (krow & 7)) * 8)];
        s[ct] = __builtin_amdgcn_mfma_f32_16x16x32_bf16(kf, qf[t], s[ct], 0, 0, 0);
      }
    }
    __builtin_amdgcn_s_setprio(0);

    // per-lane online softmax for q = l15 (exp2 domain), defer-max
    float sv[4][4];
    float mt = NEG_BIG;
#pragma unroll
    for (int ct = 0; ct < 4; ++ct)
#pragma unroll
      for (int r = 0; r < 4; ++r) {
        float x = s[ct][r] * SCALE_L2E + mv[ct][r];
        sv[ct][r] = x;
        mt = fmaxf(mt, x);
      }

    if (!__all(mt <= m_run + DEFER_THR)) {
      mt = fmaxf(mt, __shfl_xor(mt, 16, 64));
      mt = fmaxf(mt, __shfl_xor(mt, 32, 64));
      float mnew = fmaxf(m_run, mt);
      float alpha = exp2f(m_run - mnew);
      m_run = mnew;
      l_run *= alpha;
      float arow[4];
#pragma unroll
      for (int r = 0; r < 4; ++r) arow[r] = __shfl(alpha, l4 * 4 + r, 64);
#pragma unroll
      for (int dt = 0; dt < 4; ++dt)
#pragma unroll
        for (int r = 0; r < 4; ++r) o_acc[dt][r] *= arow[r];
    }

    float rsum = 0.f;
#pragma unroll
    for (int ct = 0; ct < 4; ++ct)
#pragma unroll
      for (int r = 0; r < 4; ++r) {
        float p = exp2f(sv[ct][r] - m_run);
        sv[ct][r] = p;
        rsum += p;
      }
    l_run += rsum;  // per-lane partial; cross-lane reduce deferred to end

    // P store: row q=l15, k-chunk (ct*4+l4) XOR-swizzled, b64 writes
    char* psrow = (char*)&Ps[w][0] + l15 * 128;
#pragma unroll
    for (int ct = 0; ct < 4; ++ct) {
      bf16x4 pk;
#pragma unroll
      for (int r = 0; r < 4; ++r) pk[r] = (bf16_t)sv[ct][r];
      *(bf16x4*)(psrow + (((ct * 4 + l4) ^ l15) * 8)) = pk;
    }

    // O += P V
    __builtin_amdgcn_s_setprio(1);
#pragma unroll
    for (int t = 0; t < 2; ++t) {
      int c0 = t * 8 + l4 * 2;
      bf16x4 plo = *(const bf16x4*)(psrow + ((c0 ^ l15) * 8));
      bf16x4 phi = *(const bf16x4*)(psrow + (((c0 + 1) ^ l15) * 8));
      bf16x8 pa;
#pragma unroll
      for (int j = 0; j < 4; ++j) { pa[j] = plo[j]; pa[j + 4] = phi[j]; }
#pragma unroll
      for (int dt = 0; dt < 4; ++dt) {
        int d = dt * 16 + l15;
        bf16x8 vf = *(const bf16x8*)&Vt[buf][d * 64 + (((t * 4 + l4) ^ (d & 7)) * 8)];
        o_acc[dt] = __builtin_amdgcn_mfma_f32_16x16x32_bf16(pa, vf, o_acc[dt], 0, 0, 0);
      }
    }
    __builtin_amdgcn_s_setprio(0);
    __syncthreads();
  }

  // deferred l reduction (4 lanes per q)
  float l_tot = l_run + __shfl_xor(l_run, 16, 64);
  l_tot += __shfl_xor(l_tot, 32, 64);
  float inv = 1.0f / l_tot;
  float irow[4];
#pragma unroll
  for (int r = 0; r < 4; ++r) irow[r] = __shfl(inv, l4 * 4 + r, 64);
#pragma unroll
  for (int r = 0; r < 4; ++r) {
    int qrow = qt * 32 + w * 16 + l4 * 4 + r;
#pragma unroll
    for (int dt = 0; dt < 4; ++dt) {
      int d = dt * 16 + l15;
      outx[((size_t)b * QL + qrow) * E_ + h * D_ + d] = (bf16_t)(o_acc[dt][r] * irow[r]);
    }
  }
}

// ---------------- host ----------------
extern "C" void kernel_launch(void* const* d_in, const int* in_sizes, int n_in,
                              void* d_out, int out_size, void* d_ws, size_t ws_size,
                              hipStream_t stream) {
  const float* query = (const float*)d_in[0];
  const float* key   = (const float*)d_in[1];
  const float* value = (const float*)d_in[2];
  const void*  mask  = d_in[3];
  const float* Wq = (const float*)d_in[4];
  const float* bq = (const float*)d_in[5];
  const float* Wk = (const float*)d_in[6];
  const float* bk = (const float*)d_in[7];
  const float* Wv = (const float*)d_in[8];
  const float* bv = (const float*)d_in[9];
  const float* Wo = (const float*)d_in[10];
  const float* bo = (const float*)d_in[11];

  char* ws = (char*)d_ws;
  bf16_t* Xq  = (bf16_t*)(ws + (0ull  << 20));  // 4 MB  [2048][1024]
  bf16_t* Xk  = (bf16_t*)(ws + (4ull  << 20));  // 8 MB  [4096][1024]
  bf16_t* Xv  = (bf16_t*)(ws + (12ull << 20));  // 8 MB
  bf16_t* Wqb = (bf16_t*)(ws + (20ull << 20));  // 2 MB
  bf16_t* Wkb = (bf16_t*)(ws + (22ull << 20));
  bf16_t* Wvb = (bf16_t*)(ws + (24ull << 20));
  bf16_t* Wob = (bf16_t*)(ws + (26ull << 20));
  bf16_t* qhd = (bf16_t*)(ws + (28ull << 20));  // 4 MB  [B,H,QL,D]
  bf16_t* khd = (bf16_t*)(ws + (32ull << 20));  // 8 MB  [B,H,KL,D]
  bf16_t* vht = (bf16_t*)(ws + (40ull << 20));  // 8 MB  [B,H,D,KL]  (V^T)
  bf16_t* axo = (bf16_t*)(ws + (48ull << 20));  // 4 MB  [2048][1024]
  float*  mbias = (float*)(ws + (52ull << 20)); // 16 KB

  prep_mask<<<1, 256, 0, stream>>>((const unsigned char*)mask, mbias);
  cast_all<<<7168, 256, 0, stream>>>(query, key, value, Wq, Wk, Wv, Wo,
                                     Xq, Xk, Xv, Wqb, Wkb, Wvb, Wob);
  qkv_gemm<<<640, 256, 0, stream>>>(Xq, Xk, Xv, Wqb, Wkb, Wvb, bq, bk, bv,
                                    qhd, khd, vht);
  attn_fused<<<1024, 128, 0, stream>>>(qhd, khd, vht, mbias, axo);
  gemm_nt<1><<<dim3(16, 8), 256, 0, stream>>>(axo, Wob, bo, (float*)d_out,
                                              2048, 1024, 1024, 0);
}

// Round 9
// 209.645 us; speedup vs baseline: 1.2858x; 1.0078x over previous
//
#include <hip/hip_runtime.h>

typedef __bf16 bf16_t;
typedef __bf16 bf16x4 __attribute__((ext_vector_type(4)));
typedef __bf16 bf16x8 __attribute__((ext_vector_type(8)));
typedef float f32x4 __attribute__((ext_vector_type(4)));

#define B_ 2
#define H_ 16
#define D_ 64
#define E_ 1024
#define QL 1024
#define KL 2048
#define SCALE_L2E 0.1803368801111204f  /* 0.125 * log2(e) — softmax in exp2 domain */
#define NEG_BIG -1e30f
#define DEFER_THR 8.0f

// ---------------- async global->LDS ----------------
__device__ __forceinline__ void gload_lds16(const void* g, void* lds) {
  auto* gp = reinterpret_cast<const __attribute__((address_space(1))) uint32_t*>(
      reinterpret_cast<uintptr_t>(g));
  auto* lp = reinterpret_cast<__attribute__((address_space(3))) uint32_t*>(
      reinterpret_cast<uintptr_t>(lds));
  __builtin_amdgcn_global_load_lds(gp, lp, 16, 0, 0);
}

// ---------------- all fp32->bf16 casts + mask prep in ONE kernel (grid 7169) ----------------
__global__ __launch_bounds__(256) void cast_all(
    const float* __restrict__ q, const float* __restrict__ k, const float* __restrict__ v,
    const float* __restrict__ wq, const float* __restrict__ wk,
    const float* __restrict__ wv, const float* __restrict__ wo,
    bf16_t* __restrict__ oq, bf16_t* __restrict__ ok, bf16_t* __restrict__ ov,
    bf16_t* __restrict__ owq, bf16_t* __restrict__ owk,
    bf16_t* __restrict__ owv, bf16_t* __restrict__ owo,
    const unsigned char* __restrict__ mraw, float* __restrict__ mbias) {
  __shared__ int flagMis, flagB0;
  int blk = blockIdx.x;
  if (blk == 7168) {  // mask prep: dtype auto-detect (int32 / uint8-bool / float32)
    int t = threadIdx.x;
    if (t == 0) { flagMis = 0; flagB0 = 0; }
    __syncthreads();
    int a = 0, c = 0;
    for (int i = t; i < B_ * KL; i += 256) {
      if (i & 3) a |= mraw[i]; else c |= mraw[i];
    }
    if (a) atomicOr(&flagMis, 1);
    if (c) atomicOr(&flagB0, 1);
    __syncthreads();
    int mode = (flagMis == 0) ? 0 : (flagB0 ? 1 : 2);
    for (int i = t; i < B_ * KL; i += 256) {
      int mv;
      if (mode == 0)      mv = ((const int*)mraw)[i];
      else if (mode == 1) mv = mraw[i];
      else                mv = (((const float*)mraw)[i] != 0.0f);
      mbias[i] = mv ? NEG_BIG : 0.0f;
    }
    return;
  }
  const float* in; bf16_t* out; int base;
  if (blk < 1024)      { in = q;  out = oq;  base = blk; }
  else if (blk < 3072) { in = k;  out = ok;  base = blk - 1024; }
  else if (blk < 5120) { in = v;  out = ov;  base = blk - 3072; }
  else if (blk < 5632) { in = wq; out = owq; base = blk - 5120; }
  else if (blk < 6144) { in = wk; out = owk; base = blk - 5632; }
  else if (blk < 6656) { in = wv; out = owv; base = blk - 6144; }
  else                 { in = wo; out = owo; base = blk - 6656; }
  size_t i = (size_t)base * 256 + threadIdx.x;
  float4 a = ((const float4*)in)[2 * i];
  float4 b = ((const float4*)in)[2 * i + 1];
  bf16x8 o;
  o[0] = (bf16_t)a.x; o[1] = (bf16_t)a.y; o[2] = (bf16_t)a.z; o[3] = (bf16_t)a.w;
  o[4] = (bf16_t)b.x; o[5] = (bf16_t)b.y; o[6] = (bf16_t)b.z; o[7] = (bf16_t)b.w;
  ((bf16x8*)out)[i] = o;
}

// ---------------- fused Q/K/V projection GEMMs, one launch (grid 640) ----------------
__global__ __launch_bounds__(256, 2)
void qkv_gemm(const bf16_t* __restrict__ Xq, const bf16_t* __restrict__ Xk,
              const bf16_t* __restrict__ Xv, const bf16_t* __restrict__ Wqb,
              const bf16_t* __restrict__ Wkb, const bf16_t* __restrict__ Wvb,
              const float* __restrict__ bq, const float* __restrict__ bk,
              const float* __restrict__ bv,
              bf16_t* __restrict__ qhd, bf16_t* __restrict__ khd, bf16_t* __restrict__ vht) {
  __shared__ alignas(16) bf16_t As[2][128 * 64];
  __shared__ alignas(16) bf16_t Bs[2][128 * 64];
  const int wid = blockIdx.x;
  const int work = (wid & 7) * 80 + (wid >> 3);  // XCD-chunked (640 = 8*80)

  const bf16_t *A, *W;
  const float* bias;
  bf16_t* out;
  int mode, Lshift, row0, col0;
  if (work < 128) {
    A = Xq; W = Wqb; bias = bq; out = qhd; mode = 0; Lshift = 10;
    row0 = (work >> 3) * 128; col0 = (work & 7) * 128;
  } else if (work < 384) {
    int t = work - 128;
    A = Xk; W = Wkb; bias = bk; out = khd; mode = 0; Lshift = 11;
    row0 = (t >> 3) * 128; col0 = (t & 7) * 128;
  } else {
    int t = work - 384;
    A = Wvb; W = Xv; bias = bv; out = vht; mode = 2; Lshift = 0;
    row0 = (t & 7) * 128; col0 = (t >> 3) * 128;
  }

  const int K = 1024;
  const int tid = threadIdx.x;
  const int lane = tid & 63;
  const int w = tid >> 6;
  const int l15 = lane & 15, l4 = lane >> 4;
  const int wr = w >> 1, wc = w & 1;

  f32x4 acc[4][4] = {};

  auto stage = [&](int buf, int kt) {
    const int k0 = kt * 64;
#pragma unroll
    for (int i = 0; i < 4; ++i) {
      int idx = (w * 4 + i) * 64 + lane;
      int r = idx >> 3, c = idx & 7;
      int cs = ((c ^ (r & 7)) * 8);
      gload_lds16(A + (size_t)(row0 + r) * K + k0 + cs, &As[buf][(w * 4 + i) * 512]);
      gload_lds16(W + (size_t)(col0 + r) * K + k0 + cs, &Bs[buf][(w * 4 + i) * 512]);
    }
  };

  auto compute = [&](int buf) {
#pragma unroll
    for (int t = 0; t < 2; ++t) {
      bf16x8 af[4], bfv[4];
#pragma unroll
      for (int i = 0; i < 4; ++i) {
        int r = wr * 64 + i * 16 + l15;
        af[i] = *(const bf16x8*)&As[buf][r * 64 + (((t * 4 + l4) ^ (r & 7)) * 8)];
      }
#pragma unroll
      for (int j = 0; j < 4; ++j) {
        int r = wc * 64 + j * 16 + l15;
        bfv[j] = *(const bf16x8*)&Bs[buf][r * 64 + (((t * 4 + l4) ^ (r & 7)) * 8)];
      }
#pragma unroll
      for (int i = 0; i < 4; ++i)
#pragma unroll
        for (int j = 0; j < 4; ++j)
          acc[i][j] = __builtin_amdgcn_mfma_f32_16x16x32_bf16(af[i], bfv[j], acc[i][j], 0, 0, 0);
    }
  };

  stage(0, 0);
  const int nk = K >> 6;
  for (int kt = 0; kt < nk; ++kt) {
    __syncthreads();
    if (kt + 1 < nk) stage((kt + 1) & 1, kt + 1);
    compute(kt & 1);
  }

#pragma unroll
  for (int i = 0; i < 4; ++i) {
    int mbase = row0 + wr * 64 + i * 16 + l4 * 4;
    f32x4 bvm = {};
    if (mode == 2) bvm = *(const f32x4*)&bias[mbase];
#pragma unroll
    for (int j = 0; j < 4; ++j) {
      int n = col0 + wc * 64 + j * 16 + l15;
      float bv = (mode == 2) ? 0.f : bias[n];
#pragma unroll
      for (int r = 0; r < 4; ++r) {
        float v = acc[i][j][r] + ((mode == 2) ? bvm[r] : bv);
        int m = mbase + r;
        if (mode == 0) {
          int bi = m >> Lshift;
          int ml = m & ((1 << Lshift) - 1);
          size_t dst = ((((size_t)bi * H_ + (n >> 6)) << Lshift) + ml) * D_ + (n & 63);
          out[dst] = (bf16_t)v;
        } else {
          int hh = m >> 6, d = m & 63;
          int bi = n >> 11, kk = n & (KL - 1);
          out[((((size_t)bi * H_ + hh) << 6) + d) * KL + kk] = (bf16_t)v;
        }
      }
    }
  }
}

// ---------------- O projection GEMM (fp32 out) ----------------
template <int MODE>
__global__ __launch_bounds__(256, 2)
void gemm_nt(const bf16_t* __restrict__ A, const bf16_t* __restrict__ W,
             const float* __restrict__ bias, void* __restrict__ Cout,
             int M, int N, int K, int Lshift) {
  __shared__ alignas(16) bf16_t As[2][128 * 64];
  __shared__ alignas(16) bf16_t Bs[2][128 * 64];
  const int tid = threadIdx.x;
  const int lane = tid & 63;
  const int w = tid >> 6;
  const int l15 = lane & 15, l4 = lane >> 4;
  const int wr = w >> 1, wc = w & 1;
  const int row0 = blockIdx.x * 128, col0 = blockIdx.y * 128;

  f32x4 acc[4][4] = {};

  auto stage = [&](int buf, int kt) {
    const int k0 = kt * 64;
#pragma unroll
    for (int i = 0; i < 4; ++i) {
      int idx = (w * 4 + i) * 64 + lane;
      int r = idx >> 3, c = idx & 7;
      int cs = ((c ^ (r & 7)) * 8);
      gload_lds16(A + (size_t)(row0 + r) * K + k0 + cs, &As[buf][(w * 4 + i) * 512]);
      gload_lds16(W + (size_t)(col0 + r) * K + k0 + cs, &Bs[buf][(w * 4 + i) * 512]);
    }
  };

  auto compute = [&](int buf) {
#pragma unroll
    for (int t = 0; t < 2; ++t) {
      bf16x8 af[4], bfv[4];
#pragma unroll
      for (int i = 0; i < 4; ++i) {
        int r = wr * 64 + i * 16 + l15;
        af[i] = *(const bf16x8*)&As[buf][r * 64 + (((t * 4 + l4) ^ (r & 7)) * 8)];
      }
#pragma unroll
      for (int j = 0; j < 4; ++j) {
        int r = wc * 64 + j * 16 + l15;
        bfv[j] = *(const bf16x8*)&Bs[buf][r * 64 + (((t * 4 + l4) ^ (r & 7)) * 8)];
      }
#pragma unroll
      for (int i = 0; i < 4; ++i)
#pragma unroll
        for (int j = 0; j < 4; ++j)
          acc[i][j] = __builtin_amdgcn_mfma_f32_16x16x32_bf16(af[i], bfv[j], acc[i][j], 0, 0, 0);
    }
  };

  stage(0, 0);
  const int nk = K >> 6;
  for (int kt = 0; kt < nk; ++kt) {
    __syncthreads();
    if (kt + 1 < nk) stage((kt + 1) & 1, kt + 1);
    compute(kt & 1);
  }

#pragma unroll
  for (int i = 0; i < 4; ++i) {
    int mbase = row0 + wr * 64 + i * 16 + l4 * 4;
#pragma unroll
    for (int j = 0; j < 4; ++j) {
      int n = col0 + wc * 64 + j * 16 + l15;
      float bv = bias[n];
#pragma unroll
      for (int r = 0; r < 4; ++r) {
        float v = acc[i][j][r] + bv;
        int m = mbase + r;
        ((float*)Cout)[(size_t)m * N + n] = v;
      }
    }
  }
}

// ---------------- fused flash attention, 2-way KV-split ----------------
// grid 1024 = 32 bh x 2 halves x 16 q-tiles, XCD-chunked (one (bh,half) group
// per XCD). 256 thr = 4 waves x 16 q-rows (QBLK=64). LDS 40KB -> 4 blocks/CU
// -> 16 waves/CU. Staging via hoisted pointer-increments. Unnormalized O + m,l
// partials; merged by attn_merge.
__global__ __launch_bounds__(256, 4)
void attn_fused(const bf16_t* __restrict__ qh, const bf16_t* __restrict__ kh,
                const bf16_t* __restrict__ vhT, const float* __restrict__ mbias,
                float* __restrict__ opart, float* __restrict__ marr,
                float* __restrict__ larr) {
  __shared__ alignas(16) bf16_t Ksm[2][64 * 64];
  __shared__ alignas(16) bf16_t Vt[2][64 * 64];
  __shared__ alignas(16) bf16_t Ps[4][16 * 64];

  const int wid = blockIdx.x;
  const int work = (wid & 7) * 128 + (wid >> 3);  // 1024 = 8*128 bijective
  const int qt = work & 15;
  const int half = (work >> 4) & 1;
  const int bh = work >> 5;
  const int h = bh & 15, b = bh >> 4;

  const int tid = threadIdx.x, lane = tid & 63, w = tid >> 6;
  const int l15 = lane & 15, l4 = lane >> 4;

  const bf16_t* qbase = qh + ((size_t)bh * QL + qt * 64 + w * 16) * D_;
  bf16x8 qf[2];
#pragma unroll
  for (int t = 0; t < 2; ++t)
    qf[t] = *(const bf16x8*)(qbase + l15 * D_ + t * 32 + l4 * 8);

  float m_run = NEG_BIG, l_run = 0.f;
  f32x4 o_acc[4] = {};

  // staging pointers: thread handles chunks tid and tid+256 of each 512-chunk tile
  const bf16_t* kbase = kh + ((size_t)bh * KL + half * (KL / 2)) * D_;
  const bf16_t* vtb = vhT + (size_t)bh * D_ * KL + half * (KL / 2);
  const int idx0 = tid, idx1 = tid + 256;
  const int r0 = idx0 >> 3, cs0 = ((idx0 & 7) ^ (r0 & 7)) * 8;
  const int r1 = idx1 >> 3, cs1 = ((idx1 & 7) ^ (r1 & 7)) * 8;
  const bf16_t* kp0 = kbase + r0 * D_ + cs0;
  const bf16_t* kp1 = kbase + r1 * D_ + cs1;
  const bf16_t* vp0 = vtb + (size_t)r0 * KL + cs0;
  const bf16_t* vp1 = vtb + (size_t)r1 * KL + cs1;
  const float* mptr = mbias + (size_t)b * KL + half * (KL / 2) + l4 * 4;

  auto stage = [&](int bufsel) {
    gload_lds16(kp0, &Ksm[bufsel][idx0 * 8]);
    gload_lds16(kp1, &Ksm[bufsel][idx1 * 8]);
    gload_lds16(vp0, &Vt[bufsel][idx0 * 8]);
    gload_lds16(vp1, &Vt[bufsel][idx1 * 8]);
    kp0 += 64 * D_; kp1 += 64 * D_; vp0 += 64; vp1 += 64;
  };

  stage(0);
  __syncthreads();

  const int NT = KL / 2 / 64;  // 16 tiles per half
  for (int kt = 0; kt < NT; ++kt) {
    const int buf = kt & 1;
    if (kt + 1 < NT) stage(buf ^ 1);

    f32x4 mv[4];
#pragma unroll
    for (int ct = 0; ct < 4; ++ct)
      mv[ct] = *(const f32x4*)(mptr + ct * 16);
    mptr += 64;

    // S^T = K Q^T
    f32x4 s[4] = {};
    __builtin_amdgcn_s_setprio(1);
#pragma unroll
    for (int ct = 0; ct < 4; ++ct) {
      int krow = ct * 16 + l15;
#pragma unroll
      for (int t = 0; t < 2; ++t) {
        bf16x8 kf = *(const bf16x8*)&Ksm[buf][krow * 64 + (((t * 4 + l4) ^ (krow & 7)) * 8)];
        s[ct] = __builtin_amdgcn_mfma_f32_16x16x32_bf16(kf, qf[t], s[ct], 0, 0, 0);
      }
    }
    __builtin_amdgcn_s_setprio(0);

    // per-lane online softmax for q = l15 (exp2 domain), defer-max
    float sv[4][4];
    float mt = NEG_BIG;
#pragma unroll
    for (int ct = 0; ct < 4; ++ct)
#pragma unroll
      for (int r = 0; r < 4; ++r) {
        float x = s[ct][r] * SCALE_L2E + mv[ct][r];
        sv[ct][r] = x;
        mt = fmaxf(mt, x);
      }

    if (!__all(mt <= m_run + DEFER_THR)) {
      mt = fmaxf(mt, __shfl_xor(mt, 16, 64));
      mt = fmaxf(mt, __shfl_xor(mt, 32, 64));
      float mnew = fmaxf(m_run, mt);
      float alpha = exp2f(m_run - mnew);
      m_run = mnew;
      l_run *= alpha;
      float arow[4];
#pragma unroll
      for (int r = 0; r < 4; ++r) arow[r] = __shfl(alpha, l4 * 4 + r, 64);
#pragma unroll
      for (int dt = 0; dt < 4; ++dt)
#pragma unroll
        for (int r = 0; r < 4; ++r) o_acc[dt][r] *= arow[r];
    }

    float rsum = 0.f;
#pragma unroll
    for (int ct = 0; ct < 4; ++ct)
#pragma unroll
      for (int r = 0; r < 4; ++r) {
        float p = exp2f(sv[ct][r] - m_run);
        sv[ct][r] = p;
        rsum += p;
      }
    l_run += rsum;  // per-lane partial; cross-lane reduce at end

    // P store: row q=l15, k-chunk (ct*4+l4) XOR-swizzled, b64 writes
    char* psrow = (char*)&Ps[w][0] + l15 * 128;
#pragma unroll
    for (int ct = 0; ct < 4; ++ct) {
      bf16x4 pk;
#pragma unroll
      for (int r = 0; r < 4; ++r) pk[r] = (bf16_t)sv[ct][r];
      *(bf16x4*)(psrow + (((ct * 4 + l4) ^ l15) * 8)) = pk;
    }

    // O += P V
    __builtin_amdgcn_s_setprio(1);
#pragma unroll
    for (int t = 0; t < 2; ++t) {
      int c0 = t * 8 + l4 * 2;
      bf16x4 plo = *(const bf16x4*)(psrow + ((c0 ^ l15) * 8));
      bf16x4 phi = *(const bf16x4*)(psrow + (((c0 + 1) ^ l15) * 8));
      bf16x8 pa;
#pragma unroll
      for (int j = 0; j < 4; ++j) { pa[j] = plo[j]; pa[j + 4] = phi[j]; }
#pragma unroll
      for (int dt = 0; dt < 4; ++dt) {
        int d = dt * 16 + l15;
        bf16x8 vf = *(const bf16x8*)&Vt[buf][d * 64 + (((t * 4 + l4) ^ (d & 7)) * 8)];
        o_acc[dt] = __builtin_amdgcn_mfma_f32_16x16x32_bf16(pa, vf, o_acc[dt], 0, 0, 0);
      }
    }
    __builtin_amdgcn_s_setprio(0);
    __syncthreads();
  }

  // cross-lane l reduction (4 lanes per q)
  float l_tot = l_run + __shfl_xor(l_run, 16, 64);
  l_tot += __shfl_xor(l_tot, 32, 64);

  // store unnormalized partials
  const size_t prow = (size_t)(half * 32 + bh) * QL;
#pragma unroll
  for (int r = 0; r < 4; ++r) {
    int qrow = qt * 64 + w * 16 + l4 * 4 + r;
#pragma unroll
    for (int dt = 0; dt < 4; ++dt) {
      int d = dt * 16 + l15;
      opart[(prow + qrow) * D_ + d] = o_acc[dt][r];
    }
  }
  if (l4 == 0) {
    int q = qt * 64 + w * 16 + l15;
    marr[prow + q] = m_run;
    larr[prow + q] = l_tot;
  }
}

// ---------------- merge the two KV-halves -> axo bf16 [B,QL,E] ----------------
__global__ __launch_bounds__(256)
void attn_merge(const float* __restrict__ opart, const float* __restrict__ marr,
                const float* __restrict__ larr, bf16_t* __restrict__ axo) {
  int idx = blockIdx.x * 256 + threadIdx.x;  // 262144 threads
  int row = idx >> 3;        // bh*1024 + q
  int dseg = (idx & 7) * 8;
  int bh = row >> 10, q = row & 1023;
  int b = bh >> 4, h = bh & 15;
  float m0 = marr[row], m1 = marr[32768 + row];
  float l0 = larr[row], l1 = larr[32768 + row];
  float m = fmaxf(m0, m1);
  float w0 = exp2f(m0 - m), w1 = exp2f(m1 - m);
  float denom = l0 * w0 + l1 * w1;
  float s0 = w0 / denom, s1 = w1 / denom;
  const f32x4* p0 = (const f32x4*)&opart[(size_t)row * 64 + dseg];
  const f32x4* p1 = (const f32x4*)&opart[(size_t)(32768 + row) * 64 + dseg];
  f32x4 a0 = p0[0], a1 = p0[1];
  f32x4 b0 = p1[0], b1 = p1[1];
  bf16x8 o;
#pragma unroll
  for (int i = 0; i < 4; ++i) {
    o[i]     = (bf16_t)(a0[i] * s0 + b0[i] * s1);
    o[i + 4] = (bf16_t)(a1[i] * s0 + b1[i] * s1);
  }
  *(bf16x8*)&axo[((size_t)b * QL + q) * E_ + h * 64 + dseg] = o;
}

// ---------------- host ----------------
extern "C" void kernel_launch(void* const* d_in, const int* in_sizes, int n_in,
                              void* d_out, int out_size, void* d_ws, size_t ws_size,
                              hipStream_t stream) {
  const float* query = (const float*)d_in[0];
  const float* key   = (const float*)d_in[1];
  const float* value = (const float*)d_in[2];
  const void*  mask  = d_in[3];
  const float* Wq = (const float*)d_in[4];
  const float* bq = (const float*)d_in[5];
  const float* Wk = (const float*)d_in[6];
  const float* bk = (const float*)d_in[7];
  const float* Wv = (const float*)d_in[8];
  const float* bv = (const float*)d_in[9];
  const float* Wo = (const float*)d_in[10];
  const float* bo = (const float*)d_in[11];

  char* ws = (char*)d_ws;
  bf16_t* Xq  = (bf16_t*)(ws + (0ull  << 20));  // 4 MB  [2048][1024]   (dead after qkv_gemm)
  bf16_t* Xk  = (bf16_t*)(ws + (4ull  << 20));  // 8 MB
  bf16_t* Xv  = (bf16_t*)(ws + (12ull << 20));  // 8 MB
  bf16_t* Wqb = (bf16_t*)(ws + (20ull << 20));  // 2 MB
  bf16_t* Wkb = (bf16_t*)(ws + (22ull << 20));
  bf16_t* Wvb = (bf16_t*)(ws + (24ull << 20));
  bf16_t* Wob = (bf16_t*)(ws + (26ull << 20));
  bf16_t* qhd = (bf16_t*)(ws + (28ull << 20));  // 4 MB  [B,H,QL,D]
  bf16_t* khd = (bf16_t*)(ws + (32ull << 20));  // 8 MB  [B,H,KL,D]
  bf16_t* vht = (bf16_t*)(ws + (40ull << 20));  // 8 MB  [B,H,D,KL]  (V^T)
  bf16_t* axo = (bf16_t*)(ws + (48ull << 20));  // 4 MB  [2048][1024]
  float*  mbias = (float*)(ws + (52ull << 20)); // 16 KB
  // attn partials reuse the Xq/Xk region (dead once attn_fused launches)
  float* opart = (float*)(ws + (0ull << 20));   // 16 MB [2][32][1024][64] f32
  float* marr  = (float*)(ws + (16ull << 20));  // 256 KB [2][32][1024]
  float* larr  = (float*)(ws + (17ull << 20));  // 256 KB

  cast_all<<<7169, 256, 0, stream>>>(query, key, value, Wq, Wk, Wv, Wo,
                                     Xq, Xk, Xv, Wqb, Wkb, Wvb, Wob,
                                     (const unsigned char*)mask, mbias);
  qkv_gemm<<<640, 256, 0, stream>>>(Xq, Xk, Xv, Wqb, Wkb, Wvb, bq, bk, bv,
                                    qhd, khd, vht);
  attn_fused<<<1024, 256, 0, stream>>>(qhd, khd, vht, mbias, opart, marr, larr);
  attn_merge<<<1024, 256, 0, stream>>>(opart, marr, larr, axo);
  gemm_nt<1><<<dim3(16, 8), 256, 0, stream>>>(axo, Wob, bo, (float*)d_out,
                                              2048, 1024, 1024, 0);
}